// Round 4
// baseline (980.214 us; speedup 1.0000x reference)
//
#include <hip/hip_runtime.h>
#include <hip/hip_bf16.h>

// ---------------- problem constants ----------------
#define BB 32
#define C_IN 3
#define HW 64
#define V1 1024
#define CL2_F 128
#define V2 256
#define CL3_F 256
#define FC1_IN 16384

typedef unsigned short ushortT;
typedef __attribute__((ext_vector_type(8))) short bf16x8;
typedef __attribute__((ext_vector_type(8))) unsigned short u16x8;
typedef __attribute__((ext_vector_type(4))) float f32x4;

__device__ __forceinline__ float bfu2f(unsigned short u) {
  union { unsigned int i; float f; } x; x.i = ((unsigned)u) << 16; return x.f;
}
__device__ __forceinline__ unsigned short f2bf(float v) {
  union { float f; unsigned int i; } x; x.f = v;
  unsigned r = x.i + 0x7FFFu + ((x.i >> 16) & 1u);
  return (unsigned short)(r >> 16);
}

// ---------------- conv1 (5x5 pad2) + ReLU + 2x2 maxpool ----------------
__global__ __launch_bounds__(256) void conv_pool_k(const float* __restrict__ x,
                                                   const float* __restrict__ w,
                                                   const float* __restrict__ bias,
                                                   float* __restrict__ P) {
  __shared__ float xs[3][7][72];
  __shared__ float wl[64][76];
  const int b = blockIdx.x >> 5, ph = blockIdx.x & 31;
  const int t = threadIdx.x;
  for (int i = t; i < 64 * 75; i += 256) wl[i / 75][i % 75] = w[i];
  for (int i = t; i < 3 * 7 * 72; i += 256) {
    int col = i % 72, rr = (i / 72) % 7, ci = i / (72 * 7);
    int ih = 2 * ph - 2 + rr, iw = col - 2;
    float v = 0.f;
    if (ih >= 0 && ih < HW && iw >= 0 && iw < HW)
      v = x[((b * 3 + ci) * HW + ih) * HW + iw];
    xs[ci][rr][col] = v;
  }
  __syncthreads();
  const int co = t >> 2, pq = t & 3;
  float acc[8][2][2];
#pragma unroll
  for (int i = 0; i < 8; ++i)
#pragma unroll
    for (int a = 0; a < 2; ++a)
#pragma unroll
      for (int d = 0; d < 2; ++d) acc[i][a][d] = 0.f;
  for (int ci = 0; ci < 3; ++ci) {
#pragma unroll
    for (int kh = 0; kh < 5; ++kh) {
      float w5[5];
#pragma unroll
      for (int j = 0; j < 5; ++j) w5[j] = wl[co][ci * 25 + kh * 5 + j];
#pragma unroll
      for (int dy = 0; dy < 2; ++dy) {
        const int r = kh + dy;
        float in[20];
#pragma unroll
        for (int q4 = 0; q4 < 5; ++q4) {
          float4 v4 = *(const float4*)&xs[ci][r][16 * pq + q4 * 4];
          in[q4 * 4 + 0] = v4.x; in[q4 * 4 + 1] = v4.y;
          in[q4 * 4 + 2] = v4.z; in[q4 * 4 + 3] = v4.w;
        }
#pragma unroll
        for (int i = 0; i < 8; ++i)
#pragma unroll
          for (int dx = 0; dx < 2; ++dx)
#pragma unroll
            for (int kw = 0; kw < 5; ++kw)
              acc[i][dy][dx] += w5[kw] * in[2 * i + dx + kw];
      }
    }
  }
  const float bv = bias[co];
#pragma unroll
  for (int i = 0; i < 8; ++i) {
    float m = fmaxf(fmaxf(acc[i][0][0], acc[i][0][1]), fmaxf(acc[i][1][0], acc[i][1][1]));
    P[((size_t)(b * 64 + co) << 10) + (ph << 5) + pq * 8 + i] = fmaxf(m + bv, 0.f);
  }
}

// ---------------- BN stats (2-stage) ----------------
__global__ __launch_bounds__(256) void bn_part_k(const float* __restrict__ P,
                                                 float* __restrict__ buf) {
  int c = blockIdx.x, s = blockIdx.y;
  float s1 = 0.f, s2 = 0.f;
  for (int i = threadIdx.x; i < 4096; i += 256) {
    int b = s * 4 + (i >> 10), p = i & 1023;
    float v = P[((size_t)(b * 64 + c) << 10) + p];
    s1 += v; s2 += v * v;
  }
#pragma unroll
  for (int o = 32; o > 0; o >>= 1) { s1 += __shfl_down(s1, o); s2 += __shfl_down(s2, o); }
  __shared__ float sh[2][4];
  int wid = threadIdx.x >> 6;
  if ((threadIdx.x & 63) == 0) { sh[0][wid] = s1; sh[1][wid] = s2; }
  __syncthreads();
  if (threadIdx.x == 0) {
    buf[c * 8 + s] = sh[0][0] + sh[0][1] + sh[0][2] + sh[0][3];
    buf[512 + c * 8 + s] = sh[1][0] + sh[1][1] + sh[1][2] + sh[1][3];
  }
}
__global__ __launch_bounds__(64) void bn_comb_k(float* __restrict__ buf) {
  int c = threadIdx.x;
  float s1 = 0.f, s2 = 0.f;
#pragma unroll
  for (int s = 0; s < 8; ++s) { s1 += buf[c * 8 + s]; s2 += buf[512 + c * 8 + s]; }
  float mean = s1 / 32768.f;
  float var = s2 / 32768.f - mean * mean;
  buf[1024 + c] = mean;
  buf[1088 + c] = rsqrtf(var + 1e-5f);
}

// ---------------- gather + BN -> PG pair + CW(slot0) ----------------
__global__ __launch_bounds__(256) void build_x0_k(const float* __restrict__ P,
                                                  const float* __restrict__ buf,
                                                  const int* __restrict__ ni,
                                                  const int* __restrict__ perm,
                                                  ushortT* __restrict__ PGh,
                                                  ushortT* __restrict__ PGl,
                                                  ushortT* __restrict__ CW0) {
  __shared__ float vals[64][33];
  __shared__ int qv[32];
  const int b = blockIdx.x >> 5, vc = blockIdx.x & 31;
  const int t = threadIdx.x;
  if (t < 32) {
    int pv = perm[vc * 32 + t];
    qv[t] = ni[2 * pv] * 32 + ni[2 * pv + 1];
  }
  __syncthreads();
  {
    int c = t & 63, vh = t >> 6;
    float mean = buf[1024 + c], rstd = buf[1088 + c];
    const float* pc = &P[((size_t)(b * 64 + c)) << 10];
#pragma unroll
    for (int j = 0; j < 8; ++j) {
      int vl = vh * 8 + j;
      vals[c][vl] = (pc[qv[vl]] - mean) * rstd;
    }
  }
  __syncthreads();
  {
    int c = t & 63, vo = t >> 6;
    u16x8 h8, l8;
#pragma unroll
    for (int j = 0; j < 8; ++j) {
      float f = vals[c][vo * 8 + j];
      unsigned short h = f2bf(f);
      h8[j] = h; l8[j] = f2bf(f - bfu2f(h));
    }
    size_t base = ((size_t)(vc * 4 + vo) * 2048 + b * 64 + c) * 8;
    *(u16x8*)&PGh[base] = h8;
    *(u16x8*)&PGl[base] = l8;
  }
  {
    int co = t & 7, vl = t >> 3;
    u16x8 h8;
#pragma unroll
    for (int j = 0; j < 8; ++j) h8[j] = f2bf(vals[co * 8 + j][vl]);
    *(u16x8*)&CW0[((size_t)(b * 1024 + vc * 32 + vl) * 64) + co * 8] = h8;
  }
}

// ---------------- L split fp32 -> bf16 hi/lo ----------------
__global__ __launch_bounds__(256) void lsplit_k(const float* __restrict__ L,
                                                ushortT* __restrict__ Lh,
                                                ushortT* __restrict__ Ll, int n) {
  int d = blockIdx.x * 256 + threadIdx.x;
  if (d >= n) return;
  float v = L[d];
  unsigned short h = f2bf(v);
  Lh[d] = h; Ll[d] = f2bf(v - bfu2f(h));
}

// ---------------- W prep: WA[f][kq*Cc+c] (hi/lo) ----------------
__global__ __launch_bounds__(256) void wprep_k(const float* __restrict__ W,
                                               ushortT* __restrict__ WAh,
                                               ushortT* __restrict__ WAl, int Cc, int Nf) {
  int d = blockIdx.x * 256 + threadIdx.x;
  if (d >= Nf * 16 * Cc) return;
  int c = d % Cc, kq = (d / Cc) % 16, f = d / (16 * Cc);
  float v = W[(size_t)f * (Cc * 16) + c * 16 + kq];
  unsigned short h = f2bf(v);
  WAh[d] = h; WAl[d] = f2bf(v - bfu2f(h));
}

// ---------------- Chebyshev step: LDS-free MFMA, 3-product split ----------------
// out^T[m][n] = sum_k (Ah+Al)[m][k] * L[n][k]   (L symmetric)
// MODE 0: out = D ; MODE 1: out = 2D - prev (in-place over prev pair)
template <int BM, int MODE>
__global__ __launch_bounds__(256) void cheb_step_k(
    int Mld, int Kd,
    const ushortT* __restrict__ Ah, const ushortT* __restrict__ Al,
    const ushortT* __restrict__ Lbh, const ushortT* __restrict__ Lbl,
    ushortT* __restrict__ Ph, ushortT* __restrict__ Pl,
    ushortT* __restrict__ CW, int CB, int CSH) {
  constexpr int WM = BM / 2;
  constexpr int MI = WM / 16;
  const int m0 = blockIdx.x * BM, n0 = blockIdx.y * 64;
  const int t = threadIdx.x, lane = t & 63, wid = t >> 6;
  const int wr = wid >> 1, wc = wid & 1;
  const int lm = lane & 15, lq = lane >> 4;

  // A frag (s,mi) at Ah[aBase + s*aS + mi*128]
  const size_t aBase = ((size_t)lq * Mld + (m0 + wr * WM + lm)) * 8;
  const size_t aS = (size_t)Mld * 32;
  // B frag (s,nj) at Lbh[bBase + s*32 + nj*16*Kd]
  const size_t bBase = (size_t)(n0 + wc * 32 + lm) * Kd + lq * 8;
  const size_t bNJ = (size_t)16 * Kd;

  f32x4 acc[MI][2];
#pragma unroll
  for (int mi = 0; mi < MI; ++mi)
#pragma unroll
    for (int nj = 0; nj < 2; ++nj) acc[mi][nj] = (f32x4){0.f, 0.f, 0.f, 0.f};

  bf16x8 Xah[MI], Xal[MI], Xbh[2], Xbl[2];
  bf16x8 Yah[MI], Yal[MI], Ybh[2], Ybl[2];

#define CHEB_LOAD(Fah, Fal, Fbh, Fbl, s)                                          \
  {                                                                               \
    _Pragma("unroll") for (int mi = 0; mi < MI; ++mi) {                           \
      size_t o = aBase + (size_t)(s)*aS + mi * 128;                               \
      Fah[mi] = *(const bf16x8*)(Ah + o);                                         \
      Fal[mi] = *(const bf16x8*)(Al + o);                                         \
    }                                                                             \
    _Pragma("unroll") for (int nj = 0; nj < 2; ++nj) {                            \
      size_t o = bBase + (size_t)(s)*32 + nj * bNJ;                               \
      Fbh[nj] = *(const bf16x8*)(Lbh + o);                                        \
      Fbl[nj] = *(const bf16x8*)(Lbl + o);                                        \
    }                                                                             \
  }

#define CHEB_MFMA(Fah, Fal, Fbh, Fbl)                                             \
  {                                                                               \
    _Pragma("unroll") for (int mi = 0; mi < MI; ++mi)                             \
        _Pragma("unroll") for (int nj = 0; nj < 2; ++nj) {                        \
      acc[mi][nj] = __builtin_amdgcn_mfma_f32_16x16x32_bf16(Fah[mi], Fbh[nj],     \
                                                            acc[mi][nj], 0, 0, 0);\
      acc[mi][nj] = __builtin_amdgcn_mfma_f32_16x16x32_bf16(Fal[mi], Fbh[nj],     \
                                                            acc[mi][nj], 0, 0, 0);\
      acc[mi][nj] = __builtin_amdgcn_mfma_f32_16x16x32_bf16(Fah[mi], Fbl[nj],     \
                                                            acc[mi][nj], 0, 0, 0);\
    }                                                                             \
  }

  const int S = Kd / 32;  // even (32 for gc1, 8 for gc2)
  CHEB_LOAD(Xah, Xal, Xbh, Xbl, 0);
  for (int s = 0; s + 2 < S; s += 2) {
    CHEB_LOAD(Yah, Yal, Ybh, Ybl, s + 1);
    CHEB_MFMA(Xah, Xal, Xbh, Xbl);
    CHEB_LOAD(Xah, Xal, Xbh, Xbl, s + 2);
    CHEB_MFMA(Yah, Yal, Ybh, Ybl);
  }
  CHEB_LOAD(Yah, Yal, Ybh, Ybl, S - 1);
  CHEB_MFMA(Xah, Xal, Xbh, Xbl);
  CHEB_MFMA(Yah, Yal, Ybh, Ybl);
#undef CHEB_LOAD
#undef CHEB_MFMA

#pragma unroll
  for (int mi = 0; mi < MI; ++mi)
#pragma unroll
    for (int nj = 0; nj < 2; ++nj) {
      const int gmb = m0 + wr * WM + mi * 16 + lq * 4;
      const int gn = n0 + wc * 32 + nj * 16 + lm;
      unsigned short cw4[4];
#pragma unroll
      for (int j = 0; j < 4; ++j) {
        int gm = gmb + j;
        size_t g = ((size_t)(gn >> 3) * Mld + gm) * 8 + (gn & 7);
        float d = acc[mi][nj][j];
        float nv;
        if (MODE == 0) nv = d;
        else nv = 2.f * d - (bfu2f(Ph[g]) + bfu2f(Pl[g]));
        unsigned short h = f2bf(nv);
        Ph[g] = h;
        Pl[g] = f2bf(nv - bfu2f(h));
        cw4[j] = h;
      }
      const int c0 = gmb & (CB - 1), bidx = gmb >> CSH;
      size_t cbase = ((size_t)bidx * Kd + gn) * CB + c0;
      uint2 u;
      u.x = (unsigned)cw4[0] | ((unsigned)cw4[1] << 16);
      u.y = (unsigned)cw4[2] | ((unsigned)cw4[3] << 16);
      *(uint2*)&CW[cbase] = u;
    }
}

// ---------------- weight apply: LDS-free MFMA, W hi/lo x X hi ----------------
// OUT[f][n] (+)= sum over 4 states, Cc chans
template <int Cc, int MODE>
__global__ __launch_bounds__(256) void wapply_k(
    int NN, int ldw, int koff,
    const ushortT* __restrict__ WAh, const ushortT* __restrict__ WAl,
    const ushortT* __restrict__ cw0, const ushortT* __restrict__ cw1,
    const ushortT* __restrict__ cw2, const ushortT* __restrict__ cw3,
    float* __restrict__ OUT) {
  constexpr int S = Cc / 8;  // 8 (gc1) / 16 (gc2)
  const int m0 = blockIdx.x * 64, n0 = blockIdx.y * 128;
  const int t = threadIdx.x, lane = t & 63, wid = t >> 6;
  const int wr = wid >> 1, wc = wid & 1;
  const int lm = lane & 15, lq = lane >> 4;

  const size_t wBase = (size_t)(m0 + wr * 32 + lm) * ldw + koff + lq * 8;
  const int nb = n0 + wc * 64 + lm;

  f32x4 acc[2][4];
#pragma unroll
  for (int mi = 0; mi < 2; ++mi)
#pragma unroll
    for (int nj = 0; nj < 4; ++nj) acc[mi][nj] = (f32x4){0.f, 0.f, 0.f, 0.f};

#pragma unroll
  for (int s = 0; s < S; ++s) {
    const int buf = (Cc == 64) ? (s >> 1) : (s >> 2);
    const ushortT* xb = (buf == 0) ? cw0 : (buf == 1) ? cw1 : (buf == 2) ? cw2 : cw3;
    const int lo = (Cc == 64) ? ((s & 1) * 4) : ((s & 3) * 4);  // octet base in buffer
    bf16x8 wh[2], wl[2], xf[4];
#pragma unroll
    for (int mi = 0; mi < 2; ++mi) {
      size_t o = wBase + (size_t)s * 32 + mi * 16 * ldw;
      wh[mi] = *(const bf16x8*)(WAh + o);
      wl[mi] = *(const bf16x8*)(WAl + o);
    }
#pragma unroll
    for (int nj = 0; nj < 4; ++nj)
      xf[nj] = *(const bf16x8*)(xb + (size_t)(nb + nj * 16) * Cc + (lo + lq) * 8);
#pragma unroll
    for (int mi = 0; mi < 2; ++mi)
#pragma unroll
      for (int nj = 0; nj < 4; ++nj) {
        acc[mi][nj] = __builtin_amdgcn_mfma_f32_16x16x32_bf16(wh[mi], xf[nj], acc[mi][nj], 0, 0, 0);
        acc[mi][nj] = __builtin_amdgcn_mfma_f32_16x16x32_bf16(wl[mi], xf[nj], acc[mi][nj], 0, 0, 0);
      }
  }

#pragma unroll
  for (int mi = 0; mi < 2; ++mi)
#pragma unroll
    for (int nj = 0; nj < 4; ++nj)
#pragma unroll
      for (int j = 0; j < 4; ++j) {
        int gm = m0 + wr * 32 + mi * 16 + lq * 4 + j;
        int gn = n0 + wc * 64 + nj * 16 + lm;
        size_t g = (size_t)gm * NN + gn;
        if (MODE == 0) OUT[g] = acc[mi][nj][j];
        else OUT[g] += acc[mi][nj][j];
      }
}

// ---------------- gc1 epilogue -> PG2 pair + CW2 slot0 ----------------
__global__ __launch_bounds__(256) void relu_pool1_k(const float* __restrict__ OUT1T,
                                                    const float* __restrict__ b2,
                                                    ushortT* __restrict__ PG2h,
                                                    ushortT* __restrict__ PG2l,
                                                    ushortT* __restrict__ CW0) {
  __shared__ float sval[128][9];
  const int b = blockIdx.x >> 5, vc = blockIdx.x & 31;
  const int t = threadIdx.x;
  {
    int f = t & 127, h = t >> 7;
    float bb = b2[f];
    const float* src = &OUT1T[(size_t)f * 32768 + b * 1024 + vc * 32];
#pragma unroll
    for (int i = 0; i < 4; ++i) {
      int v2l = h * 4 + i;
      float4 r = *(const float4*)&src[v2l * 4];
      float m = fmaxf(fmaxf(r.x, r.y), fmaxf(r.z, r.w));
      sval[f][v2l] = fmaxf(m + bb, 0.f);
    }
  }
  __syncthreads();
  if (t < 128) {
    int f = t;
    u16x8 h8, l8;
#pragma unroll
    for (int j = 0; j < 8; ++j) {
      float v = sval[f][j];
      unsigned short h = f2bf(v);
      h8[j] = h; l8[j] = f2bf(v - bfu2f(h));
    }
    size_t base = ((size_t)vc * 4096 + b * 128 + f) * 8;
    *(u16x8*)&PG2h[base] = h8;
    *(u16x8*)&PG2l[base] = l8;
  } else {
    int q = t - 128;
    int co = q & 15, v2l = q >> 4;
    u16x8 h8;
#pragma unroll
    for (int j = 0; j < 8; ++j) h8[j] = f2bf(sval[co * 8 + j][v2l]);
    *(u16x8*)&CW0[((size_t)(b * 256 + vc * 8 + v2l) * 128) + co * 8] = h8;
  }
}

// ---------------- gc2 epilogue -> At[b][f*64+v3] ----------------
__global__ __launch_bounds__(256) void relu_pool2_k(const float* __restrict__ OUT2T,
                                                    const float* __restrict__ b3,
                                                    float* __restrict__ At) {
  int n = blockIdx.x * 256 + threadIdx.x;  // 524288
  int v3 = n & 63, f = (n >> 6) & 255, b = n >> 14;
  float4 r = *(const float4*)&OUT2T[((size_t)f * 32 + b) * 256 + v3 * 4];
  float m = fmaxf(fmaxf(r.x, r.y), fmaxf(r.z, r.w));
  At[(size_t)b * FC1_IN + f * 64 + v3] = fmaxf(m + b3[f], 0.f);
}

// ---------------- fc1: LDS-tiled split-K ----------------
// grid (8 jt, 32 ks); out part[(ks*512 + j)*32 + b]
__global__ __launch_bounds__(256) void fc1_part_k(const float* __restrict__ At,
                                                  const float* __restrict__ W1,
                                                  float* __restrict__ part) {
  __shared__ float sWt[64][68];
  __shared__ float sA[64][33];
  const int jt = blockIdx.x, ks = blockIdx.y;
  const int j0 = jt * 64, kb = ks * 512;
  const int t = threadIdx.x;
  const int b = t & 31, jg = t >> 5;
  float acc[8] = {};
  for (int k0 = kb; k0 < kb + 512; k0 += 64) {
    __syncthreads();
    {  // stage W (coalesced float4), transpose into sWt[k][j]
      int jr = t >> 2, kq = t & 3;
      const float* wp = &W1[(size_t)(j0 + jr) * FC1_IN + k0 + kq * 16];
#pragma unroll
      for (int i = 0; i < 4; ++i) {
        float4 w4 = *(const float4*)(wp + 4 * i);
        int kk = kq * 16 + 4 * i;
        sWt[kk + 0][jr] = w4.x; sWt[kk + 1][jr] = w4.y;
        sWt[kk + 2][jr] = w4.z; sWt[kk + 3][jr] = w4.w;
      }
    }
    {  // stage At rows (coalesced), transpose into sA[k][b]
      int br = t >> 3, ko = t & 7;
      const float* ap = &At[(size_t)br * FC1_IN + k0 + ko * 8];
      float4 a0 = *(const float4*)ap;
      float4 a1 = *(const float4*)(ap + 4);
      int kk = ko * 8;
      sA[kk + 0][br] = a0.x; sA[kk + 1][br] = a0.y; sA[kk + 2][br] = a0.z; sA[kk + 3][br] = a0.w;
      sA[kk + 4][br] = a1.x; sA[kk + 5][br] = a1.y; sA[kk + 6][br] = a1.z; sA[kk + 7][br] = a1.w;
    }
    __syncthreads();
#pragma unroll 8
    for (int kk = 0; kk < 64; ++kk) {
      float a = sA[kk][b];
      float wv[8];
      *(float4*)wv = *(const float4*)&sWt[kk][jg * 8];
      *(float4*)(wv + 4) = *(const float4*)&sWt[kk][jg * 8 + 4];
#pragma unroll
      for (int i = 0; i < 8; ++i) acc[i] += wv[i] * a;
    }
  }
#pragma unroll
  for (int i = 0; i < 8; ++i)
    part[((size_t)ks * 512 + j0 + jg * 8 + i) * 32 + b] = acc[i];
}

__global__ __launch_bounds__(256) void fc1_combine_k(const float* __restrict__ part,
                                                     const float* __restrict__ b1,
                                                     float* __restrict__ h) {
  int n = blockIdx.x * 256 + threadIdx.x;  // 16384
  int b = n >> 9, j = n & 511;
  float s = b1[j];
#pragma unroll
  for (int ks = 0; ks < 32; ++ks) s += part[((size_t)ks * 512 + j) * 32 + b];
  h[n] = fmaxf(s, 0.f);
}

__global__ __launch_bounds__(64) void fc2_k(const float* __restrict__ h,
                                            const float* __restrict__ W2,
                                            const float* __restrict__ b2f,
                                            float* __restrict__ out) {
  int n = blockIdx.x * 64 + threadIdx.x;  // 320
  if (n >= 320) return;
  int b = n / 10, o = n % 10;
  float s = b2f[o];
  const float* hp = h + b * 512;
  const float* wp = W2 + o * 512;
  for (int j = 0; j < 512; ++j) s += hp[j] * wp[j];
  out[n] = s;
}

// ---------------- launch ----------------
extern "C" void kernel_launch(void* const* d_in, const int* in_sizes, int n_in,
                              void* d_out, int out_size, void* d_ws, size_t ws_size,
                              hipStream_t stream) {
  const float* x      = (const float*)d_in[0];
  const float* conv1w = (const float*)d_in[1];
  const float* conv1b = (const float*)d_in[2];
  const float* L1     = (const float*)d_in[3];
  const float* L2     = (const float*)d_in[4];
  const int*   ni     = (const int*)d_in[5];
  const int*   perm   = (const int*)d_in[6];
  const float* k2w    = (const float*)d_in[7];
  const float* k2b    = (const float*)d_in[8];
  const float* k3w    = (const float*)d_in[9];
  const float* k3b    = (const float*)d_in[10];
  const float* fc1w   = (const float*)d_in[11];
  const float* fc1b   = (const float*)d_in[12];
  const float* fc2w   = (const float*)d_in[13];
  const float* fc2b   = (const float*)d_in[14];
  float* out = (float*)d_out;

  char* ws = (char*)d_ws;
  const size_t MB = 1024 * 1024;
  // phase A/B
  float*   P     = (float*)(ws + 0);                 // 8MB
  ushortT* cw1[4] = {(ushortT*)(ws + 8 * MB), (ushortT*)(ws + 12 * MB),
                     (ushortT*)(ws + 16 * MB), (ushortT*)(ws + 20 * MB)};
  ushortT* pgAh = (ushortT*)(ws + 24 * MB);
  ushortT* pgAl = (ushortT*)(ws + 28 * MB);
  ushortT* pgBh = (ushortT*)(ws + 32 * MB);
  ushortT* pgBl = (ushortT*)(ws + 36 * MB);
  float*   OUT1T = (float*)(ws + 40 * MB);           // 17MB
  ushortT* L1h  = (ushortT*)(ws + 57 * MB);
  ushortT* L1l  = (ushortT*)(ws + 59 * MB);
  ushortT* WA1h = (ushortT*)(ws + 61 * MB);          // 256KB
  ushortT* WA1l = (ushortT*)(ws + 61 * MB + 262144);
  float*   BNB  = (float*)(ws + 61 * MB + 524288);   // ~5KB
  // phase C/D overlays
  ushortT* cw2[4] = {(ushortT*)(ws + 0), (ushortT*)(ws + 2 * MB),
                     (ushortT*)(ws + 4 * MB), (ushortT*)(ws + 6 * MB)};
  ushortT* pg2Ah = (ushortT*)(ws + 8 * MB);
  ushortT* pg2Al = (ushortT*)(ws + 10 * MB);
  ushortT* pg2Bh = (ushortT*)(ws + 12 * MB);
  ushortT* pg2Bl = (ushortT*)(ws + 14 * MB);
  float*   OUT2T = (float*)(ws + 16 * MB);           // 8.4MB
  ushortT* L2h  = (ushortT*)(ws + 25 * MB);
  ushortT* L2l  = (ushortT*)(ws + 25 * MB + 131072);
  ushortT* WA2h = (ushortT*)(ws + 26 * MB);          // 1MB
  ushortT* WA2l = (ushortT*)(ws + 27 * MB);
  float*   At   = (float*)(ws + 28 * MB);            // 2MB
  float*   PART = (float*)(ws + 30 * MB);            // 2MB
  float*   H    = (float*)(ws + 34 * MB);            // 64KB

  // ---- phase A ----
  conv_pool_k<<<1024, 256, 0, stream>>>(x, conv1w, conv1b, P);
  bn_part_k<<<dim3(64, 8), 256, 0, stream>>>(P, BNB);
  bn_comb_k<<<1, 64, 0, stream>>>(BNB);
  lsplit_k<<<4096, 256, 0, stream>>>(L1, L1h, L1l, 1024 * 1024);
  wprep_k<<<512, 256, 0, stream>>>(k2w, WA1h, WA1l, 64, 128);
  build_x0_k<<<1024, 256, 0, stream>>>(P, BNB, ni, perm, pgAh, pgAl, cw1[0]);

  // ---- phase B: gc1 ----
  cheb_step_k<128, 0><<<dim3(16, 16), 256, 0, stream>>>(2048, 1024, pgAh, pgAl, L1h, L1l,
                                                        pgBh, pgBl, cw1[1], 64, 6);
  for (int k = 2; k < 16; ++k) {
    ushortT *ah, *al, *oh, *ol;
    if (k & 1) { ah = pgAh; al = pgAl; oh = pgBh; ol = pgBl; }
    else       { ah = pgBh; al = pgBl; oh = pgAh; ol = pgAl; }
    cheb_step_k<128, 1><<<dim3(16, 16), 256, 0, stream>>>(2048, 1024, ah, al, L1h, L1l,
                                                          oh, ol, cw1[k & 3], 64, 6);
    if ((k & 3) == 3) {
      int kb = k >> 2;
      if (kb == 0)
        wapply_k<64, 0><<<dim3(2, 256), 256, 0, stream>>>(32768, 1024, 0, WA1h, WA1l,
                                                          cw1[0], cw1[1], cw1[2], cw1[3], OUT1T);
      else
        wapply_k<64, 1><<<dim3(2, 256), 256, 0, stream>>>(32768, 1024, kb * 256, WA1h, WA1l,
                                                          cw1[0], cw1[1], cw1[2], cw1[3], OUT1T);
    }
  }

  // ---- phase C: gc2 ----
  relu_pool1_k<<<1024, 256, 0, stream>>>(OUT1T, k2b, pg2Ah, pg2Al, cw2[0]);
  lsplit_k<<<256, 256, 0, stream>>>(L2, L2h, L2l, 65536);
  wprep_k<<<2048, 256, 0, stream>>>(k3w, WA2h, WA2l, 128, 256);

  cheb_step_k<64, 0><<<dim3(64, 4), 256, 0, stream>>>(4096, 256, pg2Ah, pg2Al, L2h, L2l,
                                                      pg2Bh, pg2Bl, cw2[1], 128, 7);
  for (int k = 2; k < 16; ++k) {
    ushortT *ah, *al, *oh, *ol;
    if (k & 1) { ah = pg2Ah; al = pg2Al; oh = pg2Bh; ol = pg2Bl; }
    else       { ah = pg2Bh; al = pg2Bl; oh = pg2Ah; ol = pg2Al; }
    cheb_step_k<64, 1><<<dim3(64, 4), 256, 0, stream>>>(4096, 256, ah, al, L2h, L2l,
                                                        oh, ol, cw2[k & 3], 128, 7);
    if ((k & 3) == 3) {
      int kb = k >> 2;
      if (kb == 0)
        wapply_k<128, 0><<<dim3(4, 64), 256, 0, stream>>>(8192, 2048, 0, WA2h, WA2l,
                                                          cw2[0], cw2[1], cw2[2], cw2[3], OUT2T);
      else
        wapply_k<128, 1><<<dim3(4, 64), 256, 0, stream>>>(8192, 2048, kb * 512, WA2h, WA2l,
                                                          cw2[0], cw2[1], cw2[2], cw2[3], OUT2T);
    }
  }

  // ---- phase D: fc ----
  relu_pool2_k<<<2048, 256, 0, stream>>>(OUT2T, k3b, At);
  fc1_part_k<<<dim3(8, 32), 256, 0, stream>>>(At, fc1w, PART);
  fc1_combine_k<<<64, 256, 0, stream>>>(PART, fc1b, H);
  fc2_k<<<5, 64, 0, stream>>>(H, fc2w, fc2b, out);
}

// Round 5
// 772.714 us; speedup vs baseline: 1.2685x; 1.2685x over previous
//
#include <hip/hip_runtime.h>
#include <hip/hip_bf16.h>

// ---------------- problem constants ----------------
#define BB 32
#define C_IN 3
#define HW 64
#define V1 1024
#define CL2_F 128
#define V2 256
#define CL3_F 256
#define FC1_IN 16384

typedef unsigned short ushortT;
typedef __attribute__((ext_vector_type(8))) short bf16x8;
typedef __attribute__((ext_vector_type(8))) unsigned short u16x8;
typedef __attribute__((ext_vector_type(4))) float f32x4;

__device__ __forceinline__ float bfu2f(unsigned short u) {
  union { unsigned int i; float f; } x; x.i = ((unsigned)u) << 16; return x.f;
}
__device__ __forceinline__ unsigned short f2bf(float v) {
  union { float f; unsigned int i; } x; x.f = v;
  unsigned r = x.i + 0x7FFFu + ((x.i >> 16) & 1u);
  return (unsigned short)(r >> 16);
}
__device__ __forceinline__ void gload16(const ushortT* g, ushortT* l) {
  __builtin_amdgcn_global_load_lds((const __attribute__((address_space(1))) void*)g,
                                   (__attribute__((address_space(3))) void*)l, 16, 0, 0);
}

// ---------------- conv1 (5x5 pad2) + ReLU + 2x2 maxpool ----------------
__global__ __launch_bounds__(256) void conv_pool_k(const float* __restrict__ x,
                                                   const float* __restrict__ w,
                                                   const float* __restrict__ bias,
                                                   float* __restrict__ P) {
  __shared__ float xs[3][7][72];
  __shared__ float wl[64][76];
  const int b = blockIdx.x >> 5, ph = blockIdx.x & 31;
  const int t = threadIdx.x;
  for (int i = t; i < 64 * 75; i += 256) wl[i / 75][i % 75] = w[i];
  for (int i = t; i < 3 * 7 * 72; i += 256) {
    int col = i % 72, rr = (i / 72) % 7, ci = i / (72 * 7);
    int ih = 2 * ph - 2 + rr, iw = col - 2;
    float v = 0.f;
    if (ih >= 0 && ih < HW && iw >= 0 && iw < HW)
      v = x[((b * 3 + ci) * HW + ih) * HW + iw];
    xs[ci][rr][col] = v;
  }
  __syncthreads();
  const int co = t >> 2, pq = t & 3;
  float acc[8][2][2];
#pragma unroll
  for (int i = 0; i < 8; ++i)
#pragma unroll
    for (int a = 0; a < 2; ++a)
#pragma unroll
      for (int d = 0; d < 2; ++d) acc[i][a][d] = 0.f;
  for (int ci = 0; ci < 3; ++ci) {
#pragma unroll
    for (int kh = 0; kh < 5; ++kh) {
      float w5[5];
#pragma unroll
      for (int j = 0; j < 5; ++j) w5[j] = wl[co][ci * 25 + kh * 5 + j];
#pragma unroll
      for (int dy = 0; dy < 2; ++dy) {
        const int r = kh + dy;
        float in[20];
#pragma unroll
        for (int q4 = 0; q4 < 5; ++q4) {
          float4 v4 = *(const float4*)&xs[ci][r][16 * pq + q4 * 4];
          in[q4 * 4 + 0] = v4.x; in[q4 * 4 + 1] = v4.y;
          in[q4 * 4 + 2] = v4.z; in[q4 * 4 + 3] = v4.w;
        }
#pragma unroll
        for (int i = 0; i < 8; ++i)
#pragma unroll
          for (int dx = 0; dx < 2; ++dx)
#pragma unroll
            for (int kw = 0; kw < 5; ++kw)
              acc[i][dy][dx] += w5[kw] * in[2 * i + dx + kw];
      }
    }
  }
  const float bv = bias[co];
#pragma unroll
  for (int i = 0; i < 8; ++i) {
    float m = fmaxf(fmaxf(acc[i][0][0], acc[i][0][1]), fmaxf(acc[i][1][0], acc[i][1][1]));
    P[((size_t)(b * 64 + co) << 10) + (ph << 5) + pq * 8 + i] = fmaxf(m + bv, 0.f);
  }
}

// ---------------- BN stats (2-stage) ----------------
__global__ __launch_bounds__(256) void bn_part_k(const float* __restrict__ P,
                                                 float* __restrict__ buf) {
  int c = blockIdx.x, s = blockIdx.y;
  float s1 = 0.f, s2 = 0.f;
  for (int i = threadIdx.x; i < 4096; i += 256) {
    int b = s * 4 + (i >> 10), p = i & 1023;
    float v = P[((size_t)(b * 64 + c) << 10) + p];
    s1 += v; s2 += v * v;
  }
#pragma unroll
  for (int o = 32; o > 0; o >>= 1) { s1 += __shfl_down(s1, o); s2 += __shfl_down(s2, o); }
  __shared__ float sh[2][4];
  int wid = threadIdx.x >> 6;
  if ((threadIdx.x & 63) == 0) { sh[0][wid] = s1; sh[1][wid] = s2; }
  __syncthreads();
  if (threadIdx.x == 0) {
    buf[c * 8 + s] = sh[0][0] + sh[0][1] + sh[0][2] + sh[0][3];
    buf[512 + c * 8 + s] = sh[1][0] + sh[1][1] + sh[1][2] + sh[1][3];
  }
}
__global__ __launch_bounds__(64) void bn_comb_k(float* __restrict__ buf) {
  int c = threadIdx.x;
  float s1 = 0.f, s2 = 0.f;
#pragma unroll
  for (int s = 0; s < 8; ++s) { s1 += buf[c * 8 + s]; s2 += buf[512 + c * 8 + s]; }
  float mean = s1 / 32768.f;
  float var = s2 / 32768.f - mean * mean;
  buf[1024 + c] = mean;
  buf[1088 + c] = rsqrtf(var + 1e-5f);
}

// ---------------- gather + BN -> PG pair + CW(slot0) ----------------
__global__ __launch_bounds__(256) void build_x0_k(const float* __restrict__ P,
                                                  const float* __restrict__ buf,
                                                  const int* __restrict__ ni,
                                                  const int* __restrict__ perm,
                                                  ushortT* __restrict__ PGh,
                                                  ushortT* __restrict__ PGl,
                                                  ushortT* __restrict__ CW0) {
  __shared__ float vals[64][33];
  __shared__ int qv[32];
  const int b = blockIdx.x >> 5, vc = blockIdx.x & 31;
  const int t = threadIdx.x;
  if (t < 32) {
    int pv = perm[vc * 32 + t];
    qv[t] = ni[2 * pv] * 32 + ni[2 * pv + 1];
  }
  __syncthreads();
  {
    int c = t & 63, vh = t >> 6;
    float mean = buf[1024 + c], rstd = buf[1088 + c];
    const float* pc = &P[((size_t)(b * 64 + c)) << 10];
#pragma unroll
    for (int j = 0; j < 8; ++j) {
      int vl = vh * 8 + j;
      vals[c][vl] = (pc[qv[vl]] - mean) * rstd;
    }
  }
  __syncthreads();
  {
    int c = t & 63, vo = t >> 6;
    u16x8 h8, l8;
#pragma unroll
    for (int j = 0; j < 8; ++j) {
      float f = vals[c][vo * 8 + j];
      unsigned short h = f2bf(f);
      h8[j] = h; l8[j] = f2bf(f - bfu2f(h));
    }
    size_t base = ((size_t)(vc * 4 + vo) * 2048 + b * 64 + c) * 8;
    *(u16x8*)&PGh[base] = h8;
    *(u16x8*)&PGl[base] = l8;
  }
  {
    int co = t & 7, vl = t >> 3;
    u16x8 h8;
#pragma unroll
    for (int j = 0; j < 8; ++j) h8[j] = f2bf(vals[co * 8 + j][vl]);
    *(u16x8*)&CW0[((size_t)(b * 1024 + vc * 32 + vl) * 64) + co * 8] = h8;
  }
}

// ---------------- L split fp32 -> bf16 hi/lo ----------------
__global__ __launch_bounds__(256) void lsplit_k(const float* __restrict__ L,
                                                ushortT* __restrict__ Lh,
                                                ushortT* __restrict__ Ll, int n) {
  int d = blockIdx.x * 256 + threadIdx.x;
  if (d >= n) return;
  float v = L[d];
  unsigned short h = f2bf(v);
  Lh[d] = h; Ll[d] = f2bf(v - bfu2f(h));
}

// ---------------- W prep: WA[f][kq*Cc+c] (hi/lo) ----------------
__global__ __launch_bounds__(256) void wprep_k(const float* __restrict__ W,
                                               ushortT* __restrict__ WAh,
                                               ushortT* __restrict__ WAl, int Cc, int Nf) {
  int d = blockIdx.x * 256 + threadIdx.x;
  if (d >= Nf * 16 * Cc) return;
  int c = d % Cc, kq = (d / Cc) % 16, f = d / (16 * Cc);
  float v = W[(size_t)f * (Cc * 16) + c * 16 + kq];
  unsigned short h = f2bf(v);
  WAh[d] = h; WAl[d] = f2bf(v - bfu2f(h));
}

// ---------------- Chebyshev step: LDS double-buffered MFMA, 3-product split ----
// block 64x64, 4 waves of 32x32. BK=64 staged via global_load_lds.
// MODE 0: out = L@x ; MODE 1: out = 2*(L@x) - prev (in-place over prev pair)
template <int MODE, int SWZ>
__global__ __launch_bounds__(256, 2) void cheb_step_k(
    int Mld, int Kd, int mt,
    const ushortT* __restrict__ Ah, const ushortT* __restrict__ Al,
    const ushortT* __restrict__ Lbh, const ushortT* __restrict__ Lbl,
    ushortT* __restrict__ Ph, ushortT* __restrict__ Pl,
    ushortT* __restrict__ CW, int CB, int CSH) {
  __shared__ ushortT sA[2][2][8][520];  // [buf][hi/lo][k-octet][m*8] (+pad)
  __shared__ ushortT sB[2][2][8][520];
  int bx, by;
  if (SWZ) {  // 8-blocks-per-XCD chunks: 8x (m) x 8y per xcd-pair group
    const int id = blockIdx.x;
    const int xcd = id & 7, pos = id >> 3;
    bx = (xcd & 3) * 8 + (pos & 7);
    by = (xcd >> 2) * 8 + (pos >> 3);
  } else {
    bx = blockIdx.x % mt;
    by = blockIdx.x / mt;
  }
  const int m0 = bx * 64, n0 = by * 64;
  const int t = threadIdx.x, lane = t & 63;
  const int wr = (t >> 6) >> 1, wc = (t >> 6) & 1;
  const int lm = lane & 15, lq = lane >> 4;

  f32x4 acc[2][2];
#pragma unroll
  for (int mi = 0; mi < 2; ++mi)
#pragma unroll
    for (int nj = 0; nj < 2; ++nj) acc[mi][nj] = (f32x4){0.f, 0.f, 0.f, 0.f};

#define STAGEK(buf, k0)                                                            \
  {                                                                                \
    const int koct = (k0) >> 3;                                                    \
    _Pragma("unroll") for (int i = 0; i < 2; ++i) {                                \
      const int slot = (t + i * 256) >> 6;                                         \
      const int ln = t & 63;                                                       \
      const size_t ga = ((size_t)(koct + slot) * Mld + m0 + ln) * 8;               \
      const size_t gb = (size_t)(n0 + ln) * Kd + (k0) + slot * 8;                  \
      gload16(Ah + ga, &sA[buf][0][slot][0]);                                      \
      gload16(Al + ga, &sA[buf][1][slot][0]);                                      \
      gload16(Lbh + gb, &sB[buf][0][slot][0]);                                     \
      gload16(Lbl + gb, &sB[buf][1][slot][0]);                                     \
    }                                                                              \
  }

  STAGEK(0, 0);
  __syncthreads();
  for (int k0 = 0; k0 < Kd; k0 += 64) {
    const int cur = (k0 >> 6) & 1;
    if (k0 + 64 < Kd) STAGEK(cur ^ 1, k0 + 64);
#pragma unroll
    for (int ks = 0; ks < 2; ++ks) {
      const int so = ks * 4 + lq;
      bf16x8 xah[2], xal[2], xbh[2], xbl[2];
#pragma unroll
      for (int mi = 0; mi < 2; ++mi) {
        const int r = (wr * 32 + mi * 16 + lm) * 8;
        xah[mi] = *(const bf16x8*)&sA[cur][0][so][r];
        xal[mi] = *(const bf16x8*)&sA[cur][1][so][r];
      }
#pragma unroll
      for (int nj = 0; nj < 2; ++nj) {
        const int r = (wc * 32 + nj * 16 + lm) * 8;
        xbh[nj] = *(const bf16x8*)&sB[cur][0][so][r];
        xbl[nj] = *(const bf16x8*)&sB[cur][1][so][r];
      }
#pragma unroll
      for (int mi = 0; mi < 2; ++mi)
#pragma unroll
        for (int nj = 0; nj < 2; ++nj) {
          acc[mi][nj] = __builtin_amdgcn_mfma_f32_16x16x32_bf16(xah[mi], xbh[nj], acc[mi][nj], 0, 0, 0);
          acc[mi][nj] = __builtin_amdgcn_mfma_f32_16x16x32_bf16(xal[mi], xbh[nj], acc[mi][nj], 0, 0, 0);
          acc[mi][nj] = __builtin_amdgcn_mfma_f32_16x16x32_bf16(xah[mi], xbl[nj], acc[mi][nj], 0, 0, 0);
        }
    }
    __syncthreads();
  }
#undef STAGEK

#pragma unroll
  for (int mi = 0; mi < 2; ++mi)
#pragma unroll
    for (int nj = 0; nj < 2; ++nj) {
      const int gmb = m0 + wr * 32 + mi * 16 + lq * 4;
      const int gn = n0 + wc * 32 + nj * 16 + lm;
      unsigned short cw4[4];
#pragma unroll
      for (int j = 0; j < 4; ++j) {
        int gm = gmb + j;
        size_t g = ((size_t)(gn >> 3) * Mld + gm) * 8 + (gn & 7);
        float d = acc[mi][nj][j];
        float nv;
        if (MODE == 0) nv = d;
        else nv = 2.f * d - (bfu2f(Ph[g]) + bfu2f(Pl[g]));
        unsigned short h = f2bf(nv);
        Ph[g] = h;
        Pl[g] = f2bf(nv - bfu2f(h));
        cw4[j] = h;
      }
      const int c0 = gmb & (CB - 1), bidx = gmb >> CSH;
      size_t cbase = ((size_t)bidx * Kd + gn) * CB + c0;
      uint2 u;
      u.x = (unsigned)cw4[0] | ((unsigned)cw4[1] << 16);
      u.y = (unsigned)cw4[2] | ((unsigned)cw4[3] << 16);
      *(uint2*)&CW[cbase] = u;
    }
}

// ---------------- weight apply: single dispatch over all 16 Chebyshev terms ----
// OUT[f][n] = sum over K = 16*Cc of W * X ; X from 16 contiguous CW buffers
template <int Cc>
__global__ __launch_bounds__(256) void wapply_k(
    int NN, int ldw,
    const ushortT* __restrict__ WAh, const ushortT* __restrict__ WAl,
    const ushortT* __restrict__ cwBase, size_t cwN,
    float* __restrict__ OUT) {
  constexpr int S = Cc / 2;  // number of k-32 slots
  const int m0 = blockIdx.x * 64, n0 = blockIdx.y * 128;
  const int t = threadIdx.x, lane = t & 63, wid = t >> 6;
  const int wr = wid >> 1, wc = wid & 1;
  const int lm = lane & 15, lq = lane >> 4;

  const size_t wBase = (size_t)(m0 + wr * 32 + lm) * ldw + lq * 8;
  const int nb = n0 + wc * 64 + lm;

  f32x4 acc[2][4];
#pragma unroll
  for (int mi = 0; mi < 2; ++mi)
#pragma unroll
    for (int nj = 0; nj < 4; ++nj) acc[mi][nj] = (f32x4){0.f, 0.f, 0.f, 0.f};

#pragma unroll 4
  for (int s = 0; s < S; ++s) {
    const int buf = (Cc == 64) ? (s >> 1) : (s >> 2);
    const int lo = (Cc == 64) ? ((s & 1) * 4) : ((s & 3) * 4);
    const ushortT* xb = cwBase + (size_t)buf * cwN;
    bf16x8 wh[2], wl[2], xf[4];
#pragma unroll
    for (int mi = 0; mi < 2; ++mi) {
      size_t o = wBase + (size_t)s * 32 + (size_t)mi * 16 * ldw;
      wh[mi] = *(const bf16x8*)(WAh + o);
      wl[mi] = *(const bf16x8*)(WAl + o);
    }
#pragma unroll
    for (int nj = 0; nj < 4; ++nj)
      xf[nj] = *(const bf16x8*)(xb + (size_t)(nb + nj * 16) * Cc + (lo + lq) * 8);
#pragma unroll
    for (int mi = 0; mi < 2; ++mi)
#pragma unroll
      for (int nj = 0; nj < 4; ++nj) {
        acc[mi][nj] = __builtin_amdgcn_mfma_f32_16x16x32_bf16(wh[mi], xf[nj], acc[mi][nj], 0, 0, 0);
        acc[mi][nj] = __builtin_amdgcn_mfma_f32_16x16x32_bf16(wl[mi], xf[nj], acc[mi][nj], 0, 0, 0);
      }
  }

#pragma unroll
  for (int mi = 0; mi < 2; ++mi)
#pragma unroll
    for (int nj = 0; nj < 4; ++nj)
#pragma unroll
      for (int j = 0; j < 4; ++j) {
        int gm = m0 + wr * 32 + mi * 16 + lq * 4 + j;
        int gn = n0 + wc * 64 + nj * 16 + lm;
        OUT[(size_t)gm * NN + gn] = acc[mi][nj][j];
      }
}

// ---------------- gc1 epilogue -> PG2 pair + CW2 slot0 ----------------
__global__ __launch_bounds__(256) void relu_pool1_k(const float* __restrict__ OUT1T,
                                                    const float* __restrict__ b2,
                                                    ushortT* __restrict__ PG2h,
                                                    ushortT* __restrict__ PG2l,
                                                    ushortT* __restrict__ CW0) {
  __shared__ float sval[128][9];
  const int b = blockIdx.x >> 5, vc = blockIdx.x & 31;
  const int t = threadIdx.x;
  {
    int f = t & 127, h = t >> 7;
    float bb = b2[f];
    const float* src = &OUT1T[(size_t)f * 32768 + b * 1024 + vc * 32];
#pragma unroll
    for (int i = 0; i < 4; ++i) {
      int v2l = h * 4 + i;
      float4 r = *(const float4*)&src[v2l * 4];
      float m = fmaxf(fmaxf(r.x, r.y), fmaxf(r.z, r.w));
      sval[f][v2l] = fmaxf(m + bb, 0.f);
    }
  }
  __syncthreads();
  if (t < 128) {
    int f = t;
    u16x8 h8, l8;
#pragma unroll
    for (int j = 0; j < 8; ++j) {
      float v = sval[f][j];
      unsigned short h = f2bf(v);
      h8[j] = h; l8[j] = f2bf(v - bfu2f(h));
    }
    size_t base = ((size_t)vc * 4096 + b * 128 + f) * 8;
    *(u16x8*)&PG2h[base] = h8;
    *(u16x8*)&PG2l[base] = l8;
  } else {
    int q = t - 128;
    int co = q & 15, v2l = q >> 4;
    u16x8 h8;
#pragma unroll
    for (int j = 0; j < 8; ++j) h8[j] = f2bf(sval[co * 8 + j][v2l]);
    *(u16x8*)&CW0[((size_t)(b * 256 + vc * 8 + v2l) * 128) + co * 8] = h8;
  }
}

// ---------------- gc2 epilogue -> At[b][f*64+v3] ----------------
__global__ __launch_bounds__(256) void relu_pool2_k(const float* __restrict__ OUT2T,
                                                    const float* __restrict__ b3,
                                                    float* __restrict__ At) {
  int n = blockIdx.x * 256 + threadIdx.x;  // 524288
  int v3 = n & 63, f = (n >> 6) & 255, b = n >> 14;
  float4 r = *(const float4*)&OUT2T[((size_t)f * 32 + b) * 256 + v3 * 4];
  float m = fmaxf(fmaxf(r.x, r.y), fmaxf(r.z, r.w));
  At[(size_t)b * FC1_IN + f * 64 + v3] = fmaxf(m + b3[f], 0.f);
}

// ---------------- fc1: LDS-tiled split-K ----------------
__global__ __launch_bounds__(256) void fc1_part_k(const float* __restrict__ At,
                                                  const float* __restrict__ W1,
                                                  float* __restrict__ part) {
  __shared__ float sWt[64][68];
  __shared__ float sA[64][33];
  const int jt = blockIdx.x, ks = blockIdx.y;
  const int j0 = jt * 64, kb = ks * 512;
  const int t = threadIdx.x;
  const int b = t & 31, jg = t >> 5;
  float acc[8] = {};
  for (int k0 = kb; k0 < kb + 512; k0 += 64) {
    __syncthreads();
    {
      int jr = t >> 2, kq = t & 3;
      const float* wp = &W1[(size_t)(j0 + jr) * FC1_IN + k0 + kq * 16];
#pragma unroll
      for (int i = 0; i < 4; ++i) {
        float4 w4 = *(const float4*)(wp + 4 * i);
        int kk = kq * 16 + 4 * i;
        sWt[kk + 0][jr] = w4.x; sWt[kk + 1][jr] = w4.y;
        sWt[kk + 2][jr] = w4.z; sWt[kk + 3][jr] = w4.w;
      }
    }
    {
      int br = t >> 3, ko = t & 7;
      const float* ap = &At[(size_t)br * FC1_IN + k0 + ko * 8];
      float4 a0 = *(const float4*)ap;
      float4 a1 = *(const float4*)(ap + 4);
      int kk = ko * 8;
      sA[kk + 0][br] = a0.x; sA[kk + 1][br] = a0.y; sA[kk + 2][br] = a0.z; sA[kk + 3][br] = a0.w;
      sA[kk + 4][br] = a1.x; sA[kk + 5][br] = a1.y; sA[kk + 6][br] = a1.z; sA[kk + 7][br] = a1.w;
    }
    __syncthreads();
#pragma unroll 8
    for (int kk = 0; kk < 64; ++kk) {
      float a = sA[kk][b];
      float wv[8];
      *(float4*)wv = *(const float4*)&sWt[kk][jg * 8];
      *(float4*)(wv + 4) = *(const float4*)&sWt[kk][jg * 8 + 4];
#pragma unroll
      for (int i = 0; i < 8; ++i) acc[i] += wv[i] * a;
    }
  }
#pragma unroll
  for (int i = 0; i < 8; ++i)
    part[((size_t)ks * 512 + j0 + jg * 8 + i) * 32 + b] = acc[i];
}

__global__ __launch_bounds__(256) void fc1_combine_k(const float* __restrict__ part,
                                                     const float* __restrict__ b1,
                                                     float* __restrict__ h) {
  int n = blockIdx.x * 256 + threadIdx.x;  // 16384
  int b = n >> 9, j = n & 511;
  float s = b1[j];
#pragma unroll
  for (int ks = 0; ks < 32; ++ks) s += part[((size_t)ks * 512 + j) * 32 + b];
  h[n] = fmaxf(s, 0.f);
}

__global__ __launch_bounds__(64) void fc2_k(const float* __restrict__ h,
                                            const float* __restrict__ W2,
                                            const float* __restrict__ b2f,
                                            float* __restrict__ out) {
  int n = blockIdx.x * 64 + threadIdx.x;  // 320
  if (n >= 320) return;
  int b = n / 10, o = n % 10;
  float s = b2f[o];
  const float* hp = h + b * 512;
  const float* wp = W2 + o * 512;
  for (int j = 0; j < 512; ++j) s += hp[j] * wp[j];
  out[n] = s;
}

// ---------------- launch ----------------
extern "C" void kernel_launch(void* const* d_in, const int* in_sizes, int n_in,
                              void* d_out, int out_size, void* d_ws, size_t ws_size,
                              hipStream_t stream) {
  const float* x      = (const float*)d_in[0];
  const float* conv1w = (const float*)d_in[1];
  const float* conv1b = (const float*)d_in[2];
  const float* L1     = (const float*)d_in[3];
  const float* L2     = (const float*)d_in[4];
  const int*   ni     = (const int*)d_in[5];
  const int*   perm   = (const int*)d_in[6];
  const float* k2w    = (const float*)d_in[7];
  const float* k2b    = (const float*)d_in[8];
  const float* k3w    = (const float*)d_in[9];
  const float* k3b    = (const float*)d_in[10];
  const float* fc1w   = (const float*)d_in[11];
  const float* fc1b   = (const float*)d_in[12];
  const float* fc2w   = (const float*)d_in[13];
  const float* fc2b   = (const float*)d_in[14];
  float* out = (float*)d_out;

  char* ws = (char*)d_ws;
  const size_t MB = 1024 * 1024;
  // ---- phase A/B layout ----
  float*   P    = (float*)(ws + 0);                   // 8MB (dead after build_x0)
  ushortT* cw1  = (ushortT*)(ws + 8 * MB);            // 16 x 4MB = 64MB
  const size_t CW1N = 2u * 1024 * 1024;               // ushorts per slot
  ushortT* pgAh = (ushortT*)(ws + 72 * MB);
  ushortT* pgAl = (ushortT*)(ws + 76 * MB);
  ushortT* pgBh = (ushortT*)(ws + 80 * MB);
  ushortT* pgBl = (ushortT*)(ws + 84 * MB);
  float*   OUT1T = (float*)(ws + 88 * MB);            // 16MB
  ushortT* L1h  = (ushortT*)(ws + 105 * MB);
  ushortT* L1l  = (ushortT*)(ws + 107 * MB);
  ushortT* WA1h = (ushortT*)(ws + 109 * MB);          // 256KB
  ushortT* WA1l = (ushortT*)(ws + 109 * MB + 262144);
  float*   BNB  = (float*)(ws + 110 * MB);            // ~5KB
  // ---- phase C/D layout (over dead phase A/B regions) ----
  ushortT* cw2  = (ushortT*)(ws + 0);                 // 16 x 2MB = 32MB
  const size_t CW2N = 1024u * 1024;
  ushortT* pg2Ah = (ushortT*)(ws + 32 * MB);
  ushortT* pg2Al = (ushortT*)(ws + 34 * MB);
  ushortT* pg2Bh = (ushortT*)(ws + 36 * MB);
  ushortT* pg2Bl = (ushortT*)(ws + 38 * MB);
  float*   OUT2T = (float*)(ws + 40 * MB);            // 8MB
  ushortT* L2h  = (ushortT*)(ws + 48 * MB);
  ushortT* L2l  = (ushortT*)(ws + 48 * MB + 131072);
  ushortT* WA2h = (ushortT*)(ws + 49 * MB);           // 1MB
  ushortT* WA2l = (ushortT*)(ws + 50 * MB);
  float*   At   = (float*)(ws + 51 * MB);             // 2MB
  float*   PART = (float*)(ws + 53 * MB);             // 2MB
  float*   H    = (float*)(ws + 55 * MB);             // 64KB

  // ---- phase A ----
  conv_pool_k<<<1024, 256, 0, stream>>>(x, conv1w, conv1b, P);
  bn_part_k<<<dim3(64, 8), 256, 0, stream>>>(P, BNB);
  bn_comb_k<<<1, 64, 0, stream>>>(BNB);
  lsplit_k<<<4096, 256, 0, stream>>>(L1, L1h, L1l, 1024 * 1024);
  wprep_k<<<512, 256, 0, stream>>>(k2w, WA1h, WA1l, 64, 128);
  build_x0_k<<<1024, 256, 0, stream>>>(P, BNB, ni, perm, pgAh, pgAl, cw1 + 0 * CW1N);

  // ---- phase B: gc1 chain + single weight-apply ----
  cheb_step_k<0, 1><<<512, 256, 0, stream>>>(2048, 1024, 32, pgAh, pgAl, L1h, L1l,
                                             pgBh, pgBl, cw1 + 1 * CW1N, 64, 6);
  for (int k = 2; k < 16; ++k) {
    ushortT *ah, *al, *oh, *ol;
    if (k & 1) { ah = pgAh; al = pgAl; oh = pgBh; ol = pgBl; }
    else       { ah = pgBh; al = pgBl; oh = pgAh; ol = pgAl; }
    cheb_step_k<1, 1><<<512, 256, 0, stream>>>(2048, 1024, 32, ah, al, L1h, L1l,
                                               oh, ol, cw1 + (size_t)k * CW1N, 64, 6);
  }
  wapply_k<64><<<dim3(2, 256), 256, 0, stream>>>(32768, 1024, WA1h, WA1l, cw1, CW1N, OUT1T);

  // ---- phase C: gc2 ----
  relu_pool1_k<<<1024, 256, 0, stream>>>(OUT1T, k2b, pg2Ah, pg2Al, cw2 + 0 * CW2N);
  lsplit_k<<<256, 256, 0, stream>>>(L2, L2h, L2l, 65536);
  wprep_k<<<2048, 256, 0, stream>>>(k3w, WA2h, WA2l, 128, 256);

  cheb_step_k<0, 0><<<256, 256, 0, stream>>>(4096, 256, 64, pg2Ah, pg2Al, L2h, L2l,
                                             pg2Bh, pg2Bl, cw2 + 1 * CW2N, 128, 7);
  for (int k = 2; k < 16; ++k) {
    ushortT *ah, *al, *oh, *ol;
    if (k & 1) { ah = pg2Ah; al = pg2Al; oh = pg2Bh; ol = pg2Bl; }
    else       { ah = pg2Bh; al = pg2Bl; oh = pg2Ah; ol = pg2Al; }
    cheb_step_k<1, 0><<<256, 256, 0, stream>>>(4096, 256, 64, ah, al, L2h, L2l,
                                               oh, ol, cw2 + (size_t)k * CW2N, 128, 7);
  }
  wapply_k<128><<<dim3(4, 64), 256, 0, stream>>>(8192, 2048, WA2h, WA2l, cw2, CW2N, OUT2T);

  // ---- phase D: fc ----
  relu_pool2_k<<<2048, 256, 0, stream>>>(OUT2T, k3b, At);
  fc1_part_k<<<dim3(8, 32), 256, 0, stream>>>(At, fc1w, PART);
  fc1_combine_k<<<64, 256, 0, stream>>>(PART, fc1b, H);
  fc2_k<<<5, 64, 0, stream>>>(H, fc2w, fc2b, out);
}

// Round 6
// 606.375 us; speedup vs baseline: 1.6165x; 1.2743x over previous
//
#include <hip/hip_runtime.h>
#include <hip/hip_bf16.h>

// ---------------- problem constants ----------------
#define BB 32
#define C_IN 3
#define HW 64
#define V1 1024
#define CL2_F 128
#define V2 256
#define CL3_F 256
#define FC1_IN 16384

typedef unsigned short ushortT;
typedef __attribute__((ext_vector_type(8))) short bf16x8;
typedef __attribute__((ext_vector_type(8))) unsigned short u16x8;
typedef __attribute__((ext_vector_type(4))) float f32x4;

__device__ __forceinline__ float bfu2f(unsigned short u) {
  union { unsigned int i; float f; } x; x.i = ((unsigned)u) << 16; return x.f;
}
__device__ __forceinline__ unsigned short f2bf(float v) {
  union { float f; unsigned int i; } x; x.f = v;
  unsigned r = x.i + 0x7FFFu + ((x.i >> 16) & 1u);
  return (unsigned short)(r >> 16);
}
__device__ __forceinline__ void gload16(const ushortT* g, ushortT* l) {
  __builtin_amdgcn_global_load_lds((const __attribute__((address_space(1))) void*)g,
                                   (__attribute__((address_space(3))) void*)l, 16, 0, 0);
}

// ---------------- conv1 (5x5 pad2) + ReLU + 2x2 maxpool ----------------
__global__ __launch_bounds__(256) void conv_pool_k(const float* __restrict__ x,
                                                   const float* __restrict__ w,
                                                   const float* __restrict__ bias,
                                                   float* __restrict__ P) {
  __shared__ float xs[3][7][72];
  __shared__ float wl[64][76];
  const int b = blockIdx.x >> 5, ph = blockIdx.x & 31;
  const int t = threadIdx.x;
  for (int i = t; i < 64 * 75; i += 256) wl[i / 75][i % 75] = w[i];
  for (int i = t; i < 3 * 7 * 72; i += 256) {
    int col = i % 72, rr = (i / 72) % 7, ci = i / (72 * 7);
    int ih = 2 * ph - 2 + rr, iw = col - 2;
    float v = 0.f;
    if (ih >= 0 && ih < HW && iw >= 0 && iw < HW)
      v = x[((b * 3 + ci) * HW + ih) * HW + iw];
    xs[ci][rr][col] = v;
  }
  __syncthreads();
  const int co = t >> 2, pq = t & 3;
  float acc[8][2][2];
#pragma unroll
  for (int i = 0; i < 8; ++i)
#pragma unroll
    for (int a = 0; a < 2; ++a)
#pragma unroll
      for (int d = 0; d < 2; ++d) acc[i][a][d] = 0.f;
  for (int ci = 0; ci < 3; ++ci) {
#pragma unroll
    for (int kh = 0; kh < 5; ++kh) {
      float w5[5];
#pragma unroll
      for (int j = 0; j < 5; ++j) w5[j] = wl[co][ci * 25 + kh * 5 + j];
#pragma unroll
      for (int dy = 0; dy < 2; ++dy) {
        const int r = kh + dy;
        float in[20];
#pragma unroll
        for (int q4 = 0; q4 < 5; ++q4) {
          float4 v4 = *(const float4*)&xs[ci][r][16 * pq + q4 * 4];
          in[q4 * 4 + 0] = v4.x; in[q4 * 4 + 1] = v4.y;
          in[q4 * 4 + 2] = v4.z; in[q4 * 4 + 3] = v4.w;
        }
#pragma unroll
        for (int i = 0; i < 8; ++i)
#pragma unroll
          for (int dx = 0; dx < 2; ++dx)
#pragma unroll
            for (int kw = 0; kw < 5; ++kw)
              acc[i][dy][dx] += w5[kw] * in[2 * i + dx + kw];
      }
    }
  }
  const float bv = bias[co];
#pragma unroll
  for (int i = 0; i < 8; ++i) {
    float m = fmaxf(fmaxf(acc[i][0][0], acc[i][0][1]), fmaxf(acc[i][1][0], acc[i][1][1]));
    P[((size_t)(b * 64 + co) << 10) + (ph << 5) + pq * 8 + i] = fmaxf(m + bv, 0.f);
  }
}

// ---------------- BN stats (2-stage) ----------------
__global__ __launch_bounds__(256) void bn_part_k(const float* __restrict__ P,
                                                 float* __restrict__ buf) {
  int c = blockIdx.x, s = blockIdx.y;
  float s1 = 0.f, s2 = 0.f;
  for (int i = threadIdx.x; i < 4096; i += 256) {
    int b = s * 4 + (i >> 10), p = i & 1023;
    float v = P[((size_t)(b * 64 + c) << 10) + p];
    s1 += v; s2 += v * v;
  }
#pragma unroll
  for (int o = 32; o > 0; o >>= 1) { s1 += __shfl_down(s1, o); s2 += __shfl_down(s2, o); }
  __shared__ float sh[2][4];
  int wid = threadIdx.x >> 6;
  if ((threadIdx.x & 63) == 0) { sh[0][wid] = s1; sh[1][wid] = s2; }
  __syncthreads();
  if (threadIdx.x == 0) {
    buf[c * 8 + s] = sh[0][0] + sh[0][1] + sh[0][2] + sh[0][3];
    buf[512 + c * 8 + s] = sh[1][0] + sh[1][1] + sh[1][2] + sh[1][3];
  }
}
__global__ __launch_bounds__(64) void bn_comb_k(float* __restrict__ buf) {
  int c = threadIdx.x;
  float s1 = 0.f, s2 = 0.f;
#pragma unroll
  for (int s = 0; s < 8; ++s) { s1 += buf[c * 8 + s]; s2 += buf[512 + c * 8 + s]; }
  float mean = s1 / 32768.f;
  float var = s2 / 32768.f - mean * mean;
  buf[1024 + c] = mean;
  buf[1088 + c] = rsqrtf(var + 1e-5f);
}

// ---------------- gather + BN -> PG pair + CW(slot0, [c-oct][n][8]) ----------------
__global__ __launch_bounds__(256) void build_x0_k(const float* __restrict__ P,
                                                  const float* __restrict__ buf,
                                                  const int* __restrict__ ni,
                                                  const int* __restrict__ perm,
                                                  ushortT* __restrict__ PGh,
                                                  ushortT* __restrict__ PGl,
                                                  ushortT* __restrict__ CW0) {
  __shared__ float vals[64][33];
  __shared__ int qv[32];
  const int b = blockIdx.x >> 5, vc = blockIdx.x & 31;
  const int t = threadIdx.x;
  if (t < 32) {
    int pv = perm[vc * 32 + t];
    qv[t] = ni[2 * pv] * 32 + ni[2 * pv + 1];
  }
  __syncthreads();
  {
    int c = t & 63, vh = t >> 6;
    float mean = buf[1024 + c], rstd = buf[1088 + c];
    const float* pc = &P[((size_t)(b * 64 + c)) << 10];
#pragma unroll
    for (int j = 0; j < 8; ++j) {
      int vl = vh * 8 + j;
      vals[c][vl] = (pc[qv[vl]] - mean) * rstd;
    }
  }
  __syncthreads();
  {
    int c = t & 63, vo = t >> 6;
    u16x8 h8, l8;
#pragma unroll
    for (int j = 0; j < 8; ++j) {
      float f = vals[c][vo * 8 + j];
      unsigned short h = f2bf(f);
      h8[j] = h; l8[j] = f2bf(f - bfu2f(h));
    }
    size_t base = ((size_t)(vc * 4 + vo) * 2048 + b * 64 + c) * 8;
    *(u16x8*)&PGh[base] = h8;
    *(u16x8*)&PGl[base] = l8;
  }
  {  // CW0: c-octet co, n = b*1024 + v
    int co = t & 7, vl = t >> 3;
    u16x8 h8;
#pragma unroll
    for (int j = 0; j < 8; ++j) h8[j] = f2bf(vals[co * 8 + j][vl]);
    *(u16x8*)&CW0[((size_t)co * 32768 + b * 1024 + vc * 32 + vl) * 8] = h8;
  }
}

// ---------------- L split fp32 -> bf16 hi/lo, octet-grouped LG layout ----------
// LG[((k>>3)*V + n)*8 + (k&7)]  (L symmetric: L[k][n] == L[n][k])
__global__ __launch_bounds__(256) void lsplit_k(const float* __restrict__ L,
                                                ushortT* __restrict__ Lh,
                                                ushortT* __restrict__ Ll, int V) {
  int id = blockIdx.x * 256 + threadIdx.x;  // V*V/8
  int n = id & (V - 1), koct = id / V * 8;  // id = (koct/8)*V + n
  u16x8 h8, l8;
#pragma unroll
  for (int j = 0; j < 8; ++j) {
    float v = L[(size_t)(koct + j) * V + n];
    unsigned short h = f2bf(v);
    h8[j] = h; l8[j] = f2bf(v - bfu2f(h));
  }
  size_t o = (size_t)id * 8;
  *(u16x8*)&Lh[o] = h8;
  *(u16x8*)&Ll[o] = l8;
}

// ---------------- W prep: WA[f][kq*Cc+c] (hi/lo) ----------------
__global__ __launch_bounds__(256) void wprep_k(const float* __restrict__ W,
                                               ushortT* __restrict__ WAh,
                                               ushortT* __restrict__ WAl, int Cc, int Nf) {
  int d = blockIdx.x * 256 + threadIdx.x;
  if (d >= Nf * 16 * Cc) return;
  int c = d % Cc, kq = (d / Cc) % 16, f = d / (16 * Cc);
  float v = W[(size_t)f * (Cc * 16) + c * 16 + kq];
  unsigned short h = f2bf(v);
  WAh[d] = h; WAl[d] = f2bf(v - bfu2f(h));
}

// ---------------- Chebyshev step: LDS double-buffered MFMA, 3-product split ----
// block 64x64, 4 waves of 32x32. BK=64 staged via global_load_lds (coalesced).
// MODE 0: out = L@x ; MODE 1: out = 2*(L@x) - prev (in-place over prev pair)
template <int MODE, int SWZ>
__global__ __launch_bounds__(256, 2) void cheb_step_k(
    int Mld, int Kd, int mt,
    const ushortT* __restrict__ Ah, const ushortT* __restrict__ Al,
    const ushortT* __restrict__ Lbh, const ushortT* __restrict__ Lbl,
    ushortT* __restrict__ Ph, ushortT* __restrict__ Pl,
    ushortT* __restrict__ CW, int CB, int CSH) {
  __shared__ ushortT sA[2][2][8][520];  // [buf][hi/lo][k-octet][m*8] (+16B pad)
  __shared__ ushortT sB[2][2][8][520];
  int bx, by;
  if (SWZ) {
    const int id = blockIdx.x;
    const int xcd = id & 7, pos = id >> 3;
    bx = (xcd & 3) * 8 + (pos & 7);
    by = (xcd >> 2) * 8 + (pos >> 3);
  } else {
    bx = blockIdx.x % mt;
    by = blockIdx.x / mt;
  }
  const int m0 = bx * 64, n0 = by * 64;
  const int t = threadIdx.x, lane = t & 63;
  const int wr = (t >> 6) >> 1, wc = (t >> 6) & 1;
  const int lm = lane & 15, lq = lane >> 4;

  f32x4 acc[2][2];
#pragma unroll
  for (int mi = 0; mi < 2; ++mi)
#pragma unroll
    for (int nj = 0; nj < 2; ++nj) acc[mi][nj] = (f32x4){0.f, 0.f, 0.f, 0.f};

#define STAGEK(buf, k0)                                                            \
  {                                                                                \
    const int koct = (k0) >> 3;                                                    \
    _Pragma("unroll") for (int i = 0; i < 2; ++i) {                                \
      const int slot = (t + i * 256) >> 6;                                         \
      const int ln = t & 63;                                                       \
      const size_t ga = ((size_t)(koct + slot) * Mld + m0 + ln) * 8;               \
      const size_t gb = ((size_t)(koct + slot) * Kd + n0 + ln) * 8;                \
      gload16(Ah + ga, &sA[buf][0][slot][0]);                                      \
      gload16(Al + ga, &sA[buf][1][slot][0]);                                      \
      gload16(Lbh + gb, &sB[buf][0][slot][0]);                                     \
      gload16(Lbl + gb, &sB[buf][1][slot][0]);                                     \
    }                                                                              \
  }

  STAGEK(0, 0);
  __syncthreads();
  for (int k0 = 0; k0 < Kd; k0 += 64) {
    const int cur = (k0 >> 6) & 1;
    if (k0 + 64 < Kd) STAGEK(cur ^ 1, k0 + 64);
#pragma unroll
    for (int ks = 0; ks < 2; ++ks) {
      const int so = ks * 4 + lq;
      bf16x8 xah[2], xal[2], xbh[2], xbl[2];
#pragma unroll
      for (int mi = 0; mi < 2; ++mi) {
        const int r = (wr * 32 + mi * 16 + lm) * 8;
        xah[mi] = *(const bf16x8*)&sA[cur][0][so][r];
        xal[mi] = *(const bf16x8*)&sA[cur][1][so][r];
      }
#pragma unroll
      for (int nj = 0; nj < 2; ++nj) {
        const int r = (wc * 32 + nj * 16 + lm) * 8;
        xbh[nj] = *(const bf16x8*)&sB[cur][0][so][r];
        xbl[nj] = *(const bf16x8*)&sB[cur][1][so][r];
      }
#pragma unroll
      for (int mi = 0; mi < 2; ++mi)
#pragma unroll
        for (int nj = 0; nj < 2; ++nj) {
          acc[mi][nj] = __builtin_amdgcn_mfma_f32_16x16x32_bf16(xah[mi], xbh[nj], acc[mi][nj], 0, 0, 0);
          acc[mi][nj] = __builtin_amdgcn_mfma_f32_16x16x32_bf16(xal[mi], xbh[nj], acc[mi][nj], 0, 0, 0);
          acc[mi][nj] = __builtin_amdgcn_mfma_f32_16x16x32_bf16(xah[mi], xbl[nj], acc[mi][nj], 0, 0, 0);
        }
    }
    __syncthreads();
  }
#undef STAGEK

  // ---- epilogue via LDS transpose: all global ops vectorized u16x8 ----
  float* fs = (float*)&sA[0][0][0][0];  // [64][65] f32 tile
#pragma unroll
  for (int mi = 0; mi < 2; ++mi)
#pragma unroll
    for (int nj = 0; nj < 2; ++nj)
#pragma unroll
      for (int j = 0; j < 4; ++j) {
        int gm_l = wr * 32 + mi * 16 + lq * 4 + j;
        int gn_l = wc * 32 + nj * 16 + lm;
        fs[gm_l * 65 + gn_l] = acc[mi][nj][j];
      }
  __syncthreads();

  // Phase A: Chebyshev combine + PG pair write (row gm, gn-octet go)
  const size_t noct0 = (size_t)(n0 >> 3);
#pragma unroll
  for (int r = 0; r < 2; ++r) {
    int id = t + r * 256;
    int gm_l = id >> 3, go = id & 7;
    size_t g = ((noct0 + go) * Mld + (m0 + gm_l)) * 8;
    float nv[8];
#pragma unroll
    for (int i = 0; i < 8; ++i) nv[i] = fs[gm_l * 65 + go * 8 + i];
    if (MODE == 1) {
      u16x8 ph = *(const u16x8*)&Ph[g];
      u16x8 pl = *(const u16x8*)&Pl[g];
#pragma unroll
      for (int i = 0; i < 8; ++i) nv[i] = 2.f * nv[i] - (bfu2f(ph[i]) + bfu2f(pl[i]));
    }
    u16x8 h8, l8;
#pragma unroll
    for (int i = 0; i < 8; ++i) {
      unsigned short h = f2bf(nv[i]);
      h8[i] = h; l8[i] = f2bf(nv[i] - bfu2f(h));
    }
    *(u16x8*)&Ph[g] = h8;
    *(u16x8*)&Pl[g] = l8;
    if (MODE == 1) {
#pragma unroll
      for (int i = 0; i < 8; ++i) fs[gm_l * 65 + go * 8 + i] = nv[i];
    }
  }
  __syncthreads();

  // Phase B: CW write ([c-octet][n][8] layout, coalesced u16x8)
  const int cBase = m0 & (CB - 1);
  const int bidx = m0 >> CSH;
  const size_t NNs = (size_t)Kd << 5;  // 32 * Kd
#pragma unroll
  for (int r = 0; r < 2; ++r) {
    int id = t + r * 256;
    int gn_l = id & 63, coI = id >> 6;
    u16x8 h8;
#pragma unroll
    for (int i = 0; i < 8; ++i) h8[i] = f2bf(fs[(coI * 8 + i) * 65 + gn_l]);
    size_t cbase = ((size_t)((cBase >> 3) + coI) * NNs + (size_t)bidx * Kd + n0 + gn_l) * 8;
    *(u16x8*)&CW[cbase] = h8;
  }
}

// ---------------- weight apply: single dispatch over all 16 Chebyshev terms ----
// OUT[f][n] = sum over K = 16*Cc of W * X ; X from 16 contiguous CW buffers
template <int Cc>
__global__ __launch_bounds__(256) void wapply_k(
    int NN, int ldw,
    const ushortT* __restrict__ WAh, const ushortT* __restrict__ WAl,
    const ushortT* __restrict__ cwBase, size_t cwN,
    float* __restrict__ OUT) {
  constexpr int S = Cc / 2;  // number of k-32 slots
  const int m0 = blockIdx.x * 64, n0 = blockIdx.y * 128;
  const int t = threadIdx.x, lane = t & 63, wid = t >> 6;
  const int wr = wid >> 1, wc = wid & 1;
  const int lm = lane & 15, lq = lane >> 4;

  const size_t wBase = (size_t)(m0 + wr * 32 + lm) * ldw + lq * 8;
  const int nb = n0 + wc * 64 + lm;

  f32x4 acc[2][4];
#pragma unroll
  for (int mi = 0; mi < 2; ++mi)
#pragma unroll
    for (int nj = 0; nj < 4; ++nj) acc[mi][nj] = (f32x4){0.f, 0.f, 0.f, 0.f};

#pragma unroll 4
  for (int s = 0; s < S; ++s) {
    const int buf = (Cc == 64) ? (s >> 1) : (s >> 2);
    const int lo = (Cc == 64) ? ((s & 1) * 4) : ((s & 3) * 4);
    const ushortT* xb = cwBase + (size_t)buf * cwN;
    bf16x8 wh[2], wl[2], xf[4];
#pragma unroll
    for (int mi = 0; mi < 2; ++mi) {
      size_t o = wBase + (size_t)s * 32 + (size_t)mi * 16 * ldw;
      wh[mi] = *(const bf16x8*)(WAh + o);
      wl[mi] = *(const bf16x8*)(WAl + o);
    }
#pragma unroll
    for (int nj = 0; nj < 4; ++nj)
      xf[nj] = *(const bf16x8*)(xb + ((size_t)(lo + lq) * NN + nb + nj * 16) * 8);
#pragma unroll
    for (int mi = 0; mi < 2; ++mi)
#pragma unroll
      for (int nj = 0; nj < 4; ++nj) {
        acc[mi][nj] = __builtin_amdgcn_mfma_f32_16x16x32_bf16(wh[mi], xf[nj], acc[mi][nj], 0, 0, 0);
        acc[mi][nj] = __builtin_amdgcn_mfma_f32_16x16x32_bf16(wl[mi], xf[nj], acc[mi][nj], 0, 0, 0);
      }
  }

#pragma unroll
  for (int mi = 0; mi < 2; ++mi)
#pragma unroll
    for (int nj = 0; nj < 4; ++nj)
#pragma unroll
      for (int j = 0; j < 4; ++j) {
        int gm = m0 + wr * 32 + mi * 16 + lq * 4 + j;
        int gn = n0 + wc * 64 + nj * 16 + lm;
        OUT[(size_t)gm * NN + gn] = acc[mi][nj][j];
      }
}

// ---------------- gc1 epilogue -> PG2 pair + CW2 slot0 ----------------
__global__ __launch_bounds__(256) void relu_pool1_k(const float* __restrict__ OUT1T,
                                                    const float* __restrict__ b2,
                                                    ushortT* __restrict__ PG2h,
                                                    ushortT* __restrict__ PG2l,
                                                    ushortT* __restrict__ CW0) {
  __shared__ float sval[128][9];
  const int b = blockIdx.x >> 5, vc = blockIdx.x & 31;
  const int t = threadIdx.x;
  {
    int f = t & 127, h = t >> 7;
    float bb = b2[f];
    const float* src = &OUT1T[(size_t)f * 32768 + b * 1024 + vc * 32];
#pragma unroll
    for (int i = 0; i < 4; ++i) {
      int v2l = h * 4 + i;
      float4 r = *(const float4*)&src[v2l * 4];
      float m = fmaxf(fmaxf(r.x, r.y), fmaxf(r.z, r.w));
      sval[f][v2l] = fmaxf(m + bb, 0.f);
    }
  }
  __syncthreads();
  if (t < 128) {
    int f = t;
    u16x8 h8, l8;
#pragma unroll
    for (int j = 0; j < 8; ++j) {
      float v = sval[f][j];
      unsigned short h = f2bf(v);
      h8[j] = h; l8[j] = f2bf(v - bfu2f(h));
    }
    size_t base = ((size_t)vc * 4096 + b * 128 + f) * 8;
    *(u16x8*)&PG2h[base] = h8;
    *(u16x8*)&PG2l[base] = l8;
  } else {
    int q = t - 128;
    int co = q & 15, v2l = q >> 4;
    u16x8 h8;
#pragma unroll
    for (int j = 0; j < 8; ++j) h8[j] = f2bf(sval[co * 8 + j][v2l]);
    *(u16x8*)&CW0[((size_t)co * 8192 + b * 256 + vc * 8 + v2l) * 8] = h8;
  }
}

// ---------------- gc2 epilogue -> At[b][f*64+v3] ----------------
__global__ __launch_bounds__(256) void relu_pool2_k(const float* __restrict__ OUT2T,
                                                    const float* __restrict__ b3,
                                                    float* __restrict__ At) {
  int n = blockIdx.x * 256 + threadIdx.x;  // 524288
  int v3 = n & 63, f = (n >> 6) & 255, b = n >> 14;
  float4 r = *(const float4*)&OUT2T[((size_t)f * 32 + b) * 256 + v3 * 4];
  float m = fmaxf(fmaxf(r.x, r.y), fmaxf(r.z, r.w));
  At[(size_t)b * FC1_IN + f * 64 + v3] = fmaxf(m + b3[f], 0.f);
}

// ---------------- fc1: LDS-tiled split-K ----------------
__global__ __launch_bounds__(256) void fc1_part_k(const float* __restrict__ At,
                                                  const float* __restrict__ W1,
                                                  float* __restrict__ part) {
  __shared__ float sWt[64][68];
  __shared__ float sA[64][33];
  const int jt = blockIdx.x, ks = blockIdx.y;
  const int j0 = jt * 64, kb = ks * 512;
  const int t = threadIdx.x;
  const int b = t & 31, jg = t >> 5;
  float acc[8] = {};
  for (int k0 = kb; k0 < kb + 512; k0 += 64) {
    __syncthreads();
    {
      int jr = t >> 2, kq = t & 3;
      const float* wp = &W1[(size_t)(j0 + jr) * FC1_IN + k0 + kq * 16];
#pragma unroll
      for (int i = 0; i < 4; ++i) {
        float4 w4 = *(const float4*)(wp + 4 * i);
        int kk = kq * 16 + 4 * i;
        sWt[kk + 0][jr] = w4.x; sWt[kk + 1][jr] = w4.y;
        sWt[kk + 2][jr] = w4.z; sWt[kk + 3][jr] = w4.w;
      }
    }
    {
      int br = t >> 3, ko = t & 7;
      const float* ap = &At[(size_t)br * FC1_IN + k0 + ko * 8];
      float4 a0 = *(const float4*)ap;
      float4 a1 = *(const float4*)(ap + 4);
      int kk = ko * 8;
      sA[kk + 0][br] = a0.x; sA[kk + 1][br] = a0.y; sA[kk + 2][br] = a0.z; sA[kk + 3][br] = a0.w;
      sA[kk + 4][br] = a1.x; sA[kk + 5][br] = a1.y; sA[kk + 6][br] = a1.z; sA[kk + 7][br] = a1.w;
    }
    __syncthreads();
#pragma unroll 8
    for (int kk = 0; kk < 64; ++kk) {
      float a = sA[kk][b];
      float wv[8];
      *(float4*)wv = *(const float4*)&sWt[kk][jg * 8];
      *(float4*)(wv + 4) = *(const float4*)&sWt[kk][jg * 8 + 4];
#pragma unroll
      for (int i = 0; i < 8; ++i) acc[i] += wv[i] * a;
    }
  }
#pragma unroll
  for (int i = 0; i < 8; ++i)
    part[((size_t)ks * 512 + j0 + jg * 8 + i) * 32 + b] = acc[i];
}

__global__ __launch_bounds__(256) void fc1_combine_k(const float* __restrict__ part,
                                                     const float* __restrict__ b1,
                                                     float* __restrict__ h) {
  int n = blockIdx.x * 256 + threadIdx.x;  // 16384
  int b = n >> 9, j = n & 511;
  float s = b1[j];
#pragma unroll
  for (int ks = 0; ks < 32; ++ks) s += part[((size_t)ks * 512 + j) * 32 + b];
  h[n] = fmaxf(s, 0.f);
}

__global__ __launch_bounds__(64) void fc2_k(const float* __restrict__ h,
                                            const float* __restrict__ W2,
                                            const float* __restrict__ b2f,
                                            float* __restrict__ out) {
  int n = blockIdx.x * 64 + threadIdx.x;  // 320
  if (n >= 320) return;
  int b = n / 10, o = n % 10;
  float s = b2f[o];
  const float* hp = h + b * 512;
  const float* wp = W2 + o * 512;
  for (int j = 0; j < 512; ++j) s += hp[j] * wp[j];
  out[n] = s;
}

// ---------------- launch ----------------
extern "C" void kernel_launch(void* const* d_in, const int* in_sizes, int n_in,
                              void* d_out, int out_size, void* d_ws, size_t ws_size,
                              hipStream_t stream) {
  const float* x      = (const float*)d_in[0];
  const float* conv1w = (const float*)d_in[1];
  const float* conv1b = (const float*)d_in[2];
  const float* L1     = (const float*)d_in[3];
  const float* L2     = (const float*)d_in[4];
  const int*   ni     = (const int*)d_in[5];
  const int*   perm   = (const int*)d_in[6];
  const float* k2w    = (const float*)d_in[7];
  const float* k2b    = (const float*)d_in[8];
  const float* k3w    = (const float*)d_in[9];
  const float* k3b    = (const float*)d_in[10];
  const float* fc1w   = (const float*)d_in[11];
  const float* fc1b   = (const float*)d_in[12];
  const float* fc2w   = (const float*)d_in[13];
  const float* fc2b   = (const float*)d_in[14];
  float* out = (float*)d_out;

  char* ws = (char*)d_ws;
  const size_t MB = 1024 * 1024;
  // ---- phase A/B layout ----
  float*   P    = (float*)(ws + 0);                   // 8MB (dead after build_x0)
  ushortT* cw1  = (ushortT*)(ws + 8 * MB);            // 16 x 4MB = 64MB
  const size_t CW1N = 2u * 1024 * 1024;               // ushorts per slot
  ushortT* pgAh = (ushortT*)(ws + 72 * MB);
  ushortT* pgAl = (ushortT*)(ws + 76 * MB);
  ushortT* pgBh = (ushortT*)(ws + 80 * MB);
  ushortT* pgBl = (ushortT*)(ws + 84 * MB);
  float*   OUT1T = (float*)(ws + 88 * MB);            // 16MB
  ushortT* L1h  = (ushortT*)(ws + 105 * MB);
  ushortT* L1l  = (ushortT*)(ws + 107 * MB);
  ushortT* WA1h = (ushortT*)(ws + 109 * MB);          // 256KB
  ushortT* WA1l = (ushortT*)(ws + 109 * MB + 262144);
  float*   BNB  = (float*)(ws + 110 * MB);            // ~5KB
  // ---- phase C/D layout (over dead phase A/B regions) ----
  ushortT* cw2  = (ushortT*)(ws + 0);                 // 16 x 2MB = 32MB
  const size_t CW2N = 1024u * 1024;
  ushortT* pg2Ah = (ushortT*)(ws + 32 * MB);
  ushortT* pg2Al = (ushortT*)(ws + 34 * MB);
  ushortT* pg2Bh = (ushortT*)(ws + 36 * MB);
  ushortT* pg2Bl = (ushortT*)(ws + 38 * MB);
  float*   OUT2T = (float*)(ws + 40 * MB);            // 8MB
  ushortT* L2h  = (ushortT*)(ws + 48 * MB);
  ushortT* L2l  = (ushortT*)(ws + 48 * MB + 131072);
  ushortT* WA2h = (ushortT*)(ws + 49 * MB);           // 1MB
  ushortT* WA2l = (ushortT*)(ws + 50 * MB);
  float*   At   = (float*)(ws + 51 * MB);             // 2MB
  float*   PART = (float*)(ws + 53 * MB);             // 2MB
  float*   H    = (float*)(ws + 55 * MB);             // 64KB

  // ---- phase A ----
  conv_pool_k<<<1024, 256, 0, stream>>>(x, conv1w, conv1b, P);
  bn_part_k<<<dim3(64, 8), 256, 0, stream>>>(P, BNB);
  bn_comb_k<<<1, 64, 0, stream>>>(BNB);
  lsplit_k<<<512, 256, 0, stream>>>(L1, L1h, L1l, 1024);
  wprep_k<<<512, 256, 0, stream>>>(k2w, WA1h, WA1l, 64, 128);
  build_x0_k<<<1024, 256, 0, stream>>>(P, BNB, ni, perm, pgAh, pgAl, cw1 + 0 * CW1N);

  // ---- phase B: gc1 chain + single weight-apply ----
  cheb_step_k<0, 1><<<512, 256, 0, stream>>>(2048, 1024, 32, pgAh, pgAl, L1h, L1l,
                                             pgBh, pgBl, cw1 + 1 * CW1N, 64, 6);
  for (int k = 2; k < 16; ++k) {
    ushortT *ah, *al, *oh, *ol;
    if (k & 1) { ah = pgAh; al = pgAl; oh = pgBh; ol = pgBl; }
    else       { ah = pgBh; al = pgBl; oh = pgAh; ol = pgAl; }
    cheb_step_k<1, 1><<<512, 256, 0, stream>>>(2048, 1024, 32, ah, al, L1h, L1l,
                                               oh, ol, cw1 + (size_t)k * CW1N, 64, 6);
  }
  wapply_k<64><<<dim3(2, 256), 256, 0, stream>>>(32768, 1024, WA1h, WA1l, cw1, CW1N, OUT1T);

  // ---- phase C: gc2 ----
  relu_pool1_k<<<1024, 256, 0, stream>>>(OUT1T, k2b, pg2Ah, pg2Al, cw2 + 0 * CW2N);
  lsplit_k<<<32, 256, 0, stream>>>(L2, L2h, L2l, 256);
  wprep_k<<<2048, 256, 0, stream>>>(k3w, WA2h, WA2l, 128, 256);

  cheb_step_k<0, 0><<<256, 256, 0, stream>>>(4096, 256, 64, pg2Ah, pg2Al, L2h, L2l,
                                             pg2Bh, pg2Bl, cw2 + 1 * CW2N, 128, 7);
  for (int k = 2; k < 16; ++k) {
    ushortT *ah, *al, *oh, *ol;
    if (k & 1) { ah = pg2Ah; al = pg2Al; oh = pg2Bh; ol = pg2Bl; }
    else       { ah = pg2Bh; al = pg2Bl; oh = pg2Ah; ol = pg2Al; }
    cheb_step_k<1, 0><<<256, 256, 0, stream>>>(4096, 256, 64, ah, al, L2h, L2l,
                                               oh, ol, cw2 + (size_t)k * CW2N, 128, 7);
  }
  wapply_k<128><<<dim3(4, 64), 256, 0, stream>>>(8192, 2048, WA2h, WA2l, cw2, CW2N, OUT2T);

  // ---- phase D: fc ----
  relu_pool2_k<<<2048, 256, 0, stream>>>(OUT2T, k3b, At);
  fc1_part_k<<<dim3(8, 32), 256, 0, stream>>>(At, fc1w, PART);
  fc1_combine_k<<<64, 256, 0, stream>>>(PART, fc1b, H);
  fc2_k<<<5, 64, 0, stream>>>(H, fc2w, fc2b, out);
}